// Round 1
// 229.586 us; speedup vs baseline: 1.1825x; 1.1825x over previous
//
#include <hip/hip_runtime.h>

static constexpr int B_    = 64;
static constexpr int N_    = 2048;
static constexpr int DI_   = 8;
static constexpr int O_    = 32;
static constexpr int P_    = 16;
static constexpr int OP_   = O_ * P_;      // 512
static constexpr int M_    = OP_ * B_;     // 32768 s elements
static constexpr int CHUNK_ = 8;
static constexpr int NBLK_  = N_ / CHUNK_; // 256
static constexpr int WSLICE_ = O_ * P_ * DI_;  // 4096 floats per n

// async global->LDS, 16B per lane. LDS dest must be wave-uniform; HW writes
// dest + lane*16. Wave w stages exactly the W slice (o=2w,2w+1) that only
// wave w reads -> no cross-wave w_lds dependency, vmcnt alone synchronizes.
__device__ __forceinline__ void stage_w16(const float* g, float* l) {
  __builtin_amdgcn_global_load_lds(
      (const __attribute__((address_space(1))) void*)g,
      (__attribute__((address_space(3))) void*)l,
      16, 0, 0);
}

// MODE 0: iter0 (uniform rw; 1/32 folded into v_kernel). No softmax, no v.
// MODE 1: merged A+B per nn: preds in regs, exp-sums->z_lds, softmax, accumulate.
// MODE 2: MODE1 + write normalized rw to rw_out (v_in = v0+v1 by linearity).
// W is streamed through double-buffered LDS via global_load_lds, prefetched
// one nn ahead with counted s_waitcnt vmcnt(1) (never 0 mid-loop). This kills
// the s_load/K$ stall that made all three MODEs run at identical 64.7us.
// Register hygiene: NO address-of on private arrays, all private-array loops
// fully unrolled with constant indices (alloca/scratch was the R1/R4/R5 killer).
template <int MODE, bool ATOMIC>
__global__ __launch_bounds__(1024, 4)
void fused_pass(const float* __restrict__ x, const float* __restrict__ W,
                const float* __restrict__ v_in, float* __restrict__ s_out,
                float* __restrict__ rw_out) {
  __shared__ float x_lds[CHUNK_ * 8 * 65];              // 16.6 KB
  __shared__ __align__(16) float w_lds[2][WSLICE_];     // 32 KB, dbuf W slice
  __shared__ float z_lds[2][16 * B_];                   // 8 KB, exp partials
  const int tid  = threadIdx.x;
  const int lane = tid & 63;                 // lane == batch b
  const int wave = tid >> 6;                 // 0..15; wave owns o = 2w, 2w+1
  const int n0   = blockIdx.x * CHUNK_;

  // stage x[b][n0..n0+7][i] -> LDS (coalesced; conflict-free writes)
  #pragma unroll
  for (int k = 0; k < 4; ++k) {
    int d = k * 1024 + tid;
    int b = d >> 6, rem = d & 63;
    x_lds[rem * 65 + b] = x[b * (N_ * DI_) + n0 * DI_ + rem];
  }

  // hoist v (nn-invariant). Must be out of the loop: in-loop global loads
  // issued after a stage would force compiler vmcnt(0) and kill the prefetch.
  float va[2][16];
  if (MODE != 0) {
    #pragma unroll
    for (int oo = 0; oo < 2; ++oo) {
      const float4* vp =
          (const float4*)(v_in + (size_t)lane * OP_ + (wave * 2 + oo) * P_);
      const float4 t0 = vp[0], t1 = vp[1], t2 = vp[2], t3 = vp[3];
      va[oo][0]  = t0.x; va[oo][1]  = t0.y; va[oo][2]  = t0.z; va[oo][3]  = t0.w;
      va[oo][4]  = t1.x; va[oo][5]  = t1.y; va[oo][6]  = t1.z; va[oo][7]  = t1.w;
      va[oo][8]  = t2.x; va[oo][9]  = t2.y; va[oo][10] = t2.z; va[oo][11] = t2.w;
      va[oo][12] = t3.x; va[oo][13] = t3.y; va[oo][14] = t3.z; va[oo][15] = t3.w;
    }
  }

  float s_r[32];
  #pragma unroll
  for (int q = 0; q < 32; ++q) s_r[q] = 0.0f;

  // issue W[n0] stage LAST so it stays newest in the vmcnt queue through the
  // prologue (compiler waits for x/v loads won't drain it).
  stage_w16(W + (size_t)n0 * WSLICE_ + wave * 256 + lane * 4,
            &w_lds[0][wave * 256]);

  __syncthreads();  // x_lds ready

  #pragma unroll 1
  for (int nn = 0; nn < CHUNK_; ++nn) {
    const int n = n0 + nn;

    // prefetch W[n+1] into the other buffer, then wait for W[n] only.
    // vmcnt(1): keep the just-issued stage in flight, drain everything older
    // (stage(nn) + last iter's rw store). Never vmcnt(0) mid-loop.
    if (nn + 1 < CHUNK_) {
      stage_w16(W + (size_t)(n + 1) * WSLICE_ + wave * 256 + lane * 4,
                &w_lds[(nn + 1) & 1][wave * 256]);
      asm volatile("s_waitcnt vmcnt(1)" ::: "memory");
    } else {
      asm volatile("s_waitcnt vmcnt(0)" ::: "memory");
    }

    float xr[8];
    #pragma unroll
    for (int i = 0; i < 8; ++i) xr[i] = x_lds[(nn * 8 + i) * 65 + lane];

    float pr[2][16];
    float ao0 = 0.0f, ao1 = 0.0f;

    #pragma unroll
    for (int oo = 0; oo < 2; ++oo) {
      // wave-uniform LDS address -> broadcast ds_read_b128, conflict-free
      const float4* wl = (const float4*)&w_lds[nn & 1][(wave * 2 + oo) * 128];
      float acc = 0.0f;
      #pragma unroll
      for (int p = 0; p < P_; ++p) {
        const float4 w0 = wl[2 * p];
        const float4 w1 = wl[2 * p + 1];
        float pv = w0.x * xr[0];
        pv = __builtin_fmaf(w0.y, xr[1], pv);
        pv = __builtin_fmaf(w0.z, xr[2], pv);
        pv = __builtin_fmaf(w0.w, xr[3], pv);
        pv = __builtin_fmaf(w1.x, xr[4], pv);
        pv = __builtin_fmaf(w1.y, xr[5], pv);
        pv = __builtin_fmaf(w1.z, xr[6], pv);
        pv = __builtin_fmaf(w1.w, xr[7], pv);
        if (MODE == 0) {
          s_r[oo * 16 + p] += pv;
        } else {
          pr[oo][p] = pv;
          acc = __builtin_fmaf(pv, va[oo][p], acc);
        }
      }
      if (MODE != 0) { if (oo == 0) ao0 = acc; else ao1 = acc; }
    }

    if (MODE != 0) {
      // no-max softmax (|logit| <= ~3 analytically; exp safe in fp32).
      // Each wave contributes exp(ao0)+exp(ao1); Z = sum of 16 wave partials.
      // 2 exps + 16 LDS reads per thread instead of 32 exps + 32 reads.
      const float e0 = __expf(ao0);
      const float e1 = __expf(ao1);
      z_lds[nn & 1][wave * B_ + lane] = e0 + e1;
      __syncthreads();  // z_lds[nn&1] complete (double-buffered, one barrier)

      float Z = 0.0f;
      #pragma unroll
      for (int w = 0; w < 16; ++w) Z += z_lds[nn & 1][w * B_ + lane];
      const float rZ  = 1.0f / Z;
      const float rw0 = e0 * rZ;
      const float rw1 = e1 * rZ;

      #pragma unroll
      for (int p = 0; p < P_; ++p) {
        s_r[p]      = __builtin_fmaf(rw0, pr[0][p], s_r[p]);
        s_r[16 + p] = __builtin_fmaf(rw1, pr[1][p], s_r[16 + p]);
      }
      if (MODE == 2) {
        float2 t; t.x = rw0; t.y = rw1;
        *(float2*)(rw_out + ((size_t)lane * N_ + n) * O_ + wave * 2) = t;
      }
    }
  }

  // epilogue: block partial (layout [blk][q=o*16+p][b]) or atomic fallback
  if (ATOMIC) {
    #pragma unroll
    for (int oo = 0; oo < 2; ++oo) {
      float* sp = s_out + (size_t)((wave * 2 + oo) * P_) * B_ + lane;
      #pragma unroll
      for (int p = 0; p < P_; ++p) atomicAdd(&sp[p * B_], s_r[oo * 16 + p]);
    }
  } else {
    #pragma unroll
    for (int oo = 0; oo < 2; ++oo) {
      float* sp = s_out + (size_t)blockIdx.x * M_ +
                  (size_t)((wave * 2 + oo) * P_) * B_ + lane;
      #pragma unroll
      for (int p = 0; p < P_; ++p) sp[p * B_] = s_r[oo * 16 + p];
    }
  }
}

// stage-1 reduction: P[K][M_] -> P2[16][M_]; grid 16 groups x 16 m-chunks.
__global__ __launch_bounds__(1024)
void reduce1(const float* __restrict__ spart, float* __restrict__ p2, int K) {
  const int g  = blockIdx.x >> 4;
  const int mc = blockIdx.x & 15;
  const int kpg = K >> 4;
  const int m0 = mc * 2048 + threadIdx.x;
  float a0 = 0.0f, a1 = 0.0f;
  const float* p = spart + (size_t)(g * kpg) * M_;
  for (int k = 0; k < kpg; ++k) {
    a0 += p[(size_t)k * M_ + m0];
    a1 += p[(size_t)k * M_ + m0 + 1024];
  }
  p2[(size_t)g * M_ + m0]        = a0;
  p2[(size_t)g * M_ + m0 + 1024] = a1;
}

// sum ngroups (stride M_) + squash; optionally add v_add; optionally zero a buffer.
__global__ __launch_bounds__(1024)
void v_kernel(const float* __restrict__ src, int ngroups, float scale,
              const float* __restrict__ v_add, float* __restrict__ v_out,
              float* __restrict__ zero_buf) {
  __shared__ float sq[P_ * 64];
  const int t = threadIdx.x;
  const int b = t & 63;
  const int p = t >> 6;
  const int o = blockIdx.x;
  const int q = o * P_ + p;
  float acc = 0.0f;
  for (int g = 0; g < ngroups; ++g) acc += src[(size_t)g * M_ + q * 64 + b];
  acc *= scale;
  sq[p * 64 + b] = acc * acc;
  if (zero_buf) zero_buf[blockIdx.x * 1024 + t] = 0.0f;
  __syncthreads();
  float s2 = 0.0f;
  #pragma unroll
  for (int pp = 0; pp < P_; ++pp) s2 += sq[pp * 64 + b];
  float sc = (s2 / (1.0f + s2)) / sqrtf(s2 + 1e-7f);
  float v = acc * sc;
  const int idx = b * OP_ + q;   // v layout [b][o][p]
  v_out[idx] = v + (v_add ? v_add[idx] : 0.0f);
}

extern "C" void kernel_launch(void* const* d_in, const int* in_sizes, int n_in,
                              void* d_out, int out_size, void* d_ws, size_t ws_size,
                              hipStream_t stream) {
  (void)in_sizes; (void)n_in; (void)out_size;
  const float* x = (const float*)d_in[0];
  const float* W = (const float*)d_in[1];
  float* out_v  = (float*)d_out;                       // [64][32][16]
  float* out_rw = out_v + (size_t)B_ * O_ * P_;        // [64][2048][32]
  float* vws   = (float*)d_ws;                         // v0
  float* vsum  = vws + M_;                             // v0+v1
  float* p2    = vsum + M_;                            // 16 * M_
  float* spart = p2 + 16 * M_;                         // NBLK_ * M_

  const size_t need = (size_t)(2 * M_ + 16 * M_ + (size_t)NBLK_ * M_) * 4;

  dim3 gF(NBLK_), bF(1024), gV(O_), bV(1024), gR(256);
  if (ws_size >= need) {
    fused_pass<0, false><<<gF, bF, 0, stream>>>(x, W, nullptr, spart, nullptr);
    reduce1<<<gR, bF, 0, stream>>>(spart, p2, NBLK_);
    v_kernel<<<gV, bV, 0, stream>>>(p2, 16, 1.0f / 32.0f, nullptr, vws, nullptr);
    fused_pass<1, false><<<gF, bF, 0, stream>>>(x, W, vws, spart, nullptr);
    reduce1<<<gR, bF, 0, stream>>>(spart, p2, NBLK_);
    v_kernel<<<gV, bV, 0, stream>>>(p2, 16, 1.0f, vws, vsum, nullptr);
    fused_pass<2, false><<<gF, bF, 0, stream>>>(x, W, vsum, spart, out_rw);
    reduce1<<<gR, bF, 0, stream>>>(spart, p2, NBLK_);
    v_kernel<<<gV, bV, 0, stream>>>(p2, 16, 1.0f, nullptr, out_v, nullptr);
  } else {
    // atomic fallback for small ws
    float* sAb = p2;
    float* sBb = sAb + M_;
    hipMemsetAsync(sAb, 0, (size_t)M_ * sizeof(float), stream);
    fused_pass<0, true><<<gF, bF, 0, stream>>>(x, W, nullptr, sAb, nullptr);
    v_kernel<<<gV, bV, 0, stream>>>(sAb, 1, 1.0f / 32.0f, nullptr, vws, sBb);
    fused_pass<1, true><<<gF, bF, 0, stream>>>(x, W, vws, sBb, nullptr);
    v_kernel<<<gV, bV, 0, stream>>>(sBb, 1, 1.0f, vws, vsum, sAb);
    fused_pass<2, true><<<gF, bF, 0, stream>>>(x, W, vsum, sAb, out_rw);
    v_kernel<<<gV, bV, 0, stream>>>(sAb, 1, 1.0f, nullptr, out_v, nullptr);
  }
}